// Round 12
// baseline (204.950 us; speedup 1.0000x reference)
//
#include <hip/hip_runtime.h>

// EIT3Attention: B=4, Sq=Sk=2048, d_model=2048, H=16, Dh=128, fp32 I/O.
// R12 = R11 (64 q-rows/wave, KVB=32, no-LDS fragment-direct, M==0 softmax)
// + PREFETCH DISTANCE 2: K/V fragments triple-buffered in registers
// (3x64 = 192 regs; total ~430 <= 512 at 1 wave/SIMD). Tile t's loads are
// issued two tile-bodies (~2200 cy) before first use, so even an
// over-draining vmcnt leaves a full tile of slack. R11 diagnosis: wave
// stalled ~55-60% of cycles; MfmaUtil 34% == per-SIMD MFMA-issue floor share.

typedef __attribute__((ext_vector_type(8))) short short8;
typedef __attribute__((ext_vector_type(16))) float f32x16;

#define DEVI __device__ __forceinline__

namespace {

constexpr int DM = 2048;   // d_model
constexpr int SQ = 2048;
constexpr int SK = 2048;
constexpr int DH = 128;
constexpr int KVB = 32;            // kv rows per tile
constexpr int NT = SK / KVB;       // 64 tiles
constexpr int TILE_E = KVB * DH;   // 4096 elems per tensor-tile
// (1/sqrt(128)) * log2(e), folded into Q at conversion
constexpr float CEXP = 0.12752051393f;

union US8 { unsigned short u[8]; short8 v; };
union UP4 { unsigned int u[4]; short8 v; };

DEVI unsigned short f2bf(float f) {            // fp32 -> bf16 RNE
  unsigned int u = __float_as_uint(f);
  return (unsigned short)((u + 0x7fffu + ((u >> 16) & 1u)) >> 16);
}

DEVI float dq(float x) {                       // int4 quant-dequant, matches ref
  float t = __builtin_rintf(__builtin_fmaf(x, 20.0f, 8.0f));  // round half-even
  t = __builtin_fmaxf(t, 0.0f);
  t = __builtin_fminf(t, 15.0f);
  return (t - 8.0f) * 0.05f;
}

DEVI unsigned short dqb(float x) { return f2bf(dq(x)); }

} // namespace

// ---------------------------------------------------------------------------
// Prepass (verified R8/R9/R11): dequant K/V -> bf16 ws in MFMA-fragment order.
// Per (bh, tile t of 32 rows), granule g2 = tid (0..511), 8 elems each:
//  K: frag s = g2>>6, lane l = g2&63: Kd[t*32 + (l&31)][s*16 + (l>>5)*8 + j]
//  V: f = g2>>6 (n=f>>1, ks=f&1): Vd[t*32 + ks*16 + (l>>5)*8 + j][n*32 + (l&31)]
// ---------------------------------------------------------------------------
__global__ __launch_bounds__(512)
void eit3_pre(const float* __restrict__ kg, const float* __restrict__ vg,
              unsigned short* __restrict__ kws, unsigned short* __restrict__ vws)
{
  const int tid = threadIdx.x;
  const int t = blockIdx.x, h = blockIdx.y, b = blockIdx.z;
  const size_t tb = (((size_t)(b * 16 + h)) * NT + t) * TILE_E;
  __shared__ __align__(16) unsigned short KL[32 * 136];  // rows 16B-aligned
  __shared__ __align__(16) unsigned short VL[32 * 136];

  {
    const int r = tid >> 4, c8 = (tid & 15) * 8;
    const float* ks = kg + ((size_t)b * SK + (size_t)t * KVB + r) * DM + h * DH + c8;
    const float* vs = vg + ((size_t)b * SK + (size_t)t * KVB + r) * DM + h * DH + c8;
    float4 ka = *(const float4*)ks, kb4 = *(const float4*)(ks + 4);
    float4 va = *(const float4*)vs, vb4 = *(const float4*)(vs + 4);
    US8 ok, ov;
    ok.u[0] = dqb(ka.x); ok.u[1] = dqb(ka.y); ok.u[2] = dqb(ka.z); ok.u[3] = dqb(ka.w);
    ok.u[4] = dqb(kb4.x); ok.u[5] = dqb(kb4.y); ok.u[6] = dqb(kb4.z); ok.u[7] = dqb(kb4.w);
    ov.u[0] = dqb(va.x); ov.u[1] = dqb(va.y); ov.u[2] = dqb(va.z); ov.u[3] = dqb(va.w);
    ov.u[4] = dqb(vb4.x); ov.u[5] = dqb(vb4.y); ov.u[6] = dqb(vb4.z); ov.u[7] = dqb(vb4.w);
    *(short8*)(KL + r * 136 + c8) = ok.v;
    *(short8*)(VL + r * 136 + c8) = ov.v;
  }
  __syncthreads();

  const int l = tid & 63;
  const int lq = l & 31, lh = (l >> 5) * 8;
  {
    const int s = tid >> 6;
    short8 o = *(const short8*)(KL + lq * 136 + s * 16 + lh);
    *(short8*)(kws + tb + (size_t)tid * 8) = o;
  }
  {
    const int f = tid >> 6, n = f >> 1, ks2 = f & 1;
    US8 o;
#pragma unroll
    for (int j = 0; j < 8; ++j)
      o.u[j] = VL[(ks2 * 16 + lh + j) * 136 + n * 32 + lq];
    *(short8*)(vws + tb + (size_t)tid * 8) = o.v;
  }
}

// ---------------------------------------------------------------------------
// Main attention kernel: 1 wave/block, 64 q-rows (2 subtiles), KVB=32,
// zero LDS, M==0 softmax, K/V TRIPLE-buffered registers (prefetch dist 2).
// ---------------------------------------------------------------------------
__global__ __launch_bounds__(64)
void eit3_attn(const unsigned short* __restrict__ kws,
               const unsigned short* __restrict__ vws,
               const float* __restrict__ qg,
               const unsigned char* __restrict__ maskg,
               const int* __restrict__ qsg, float* __restrict__ outg)
{
  const int lane = threadIdx.x;
  const int hi   = lane >> 5;
  const int ql   = lane & 31;
  const int hi8  = hi * 8;
  // XCD-grouped decode: XCD x owns bh in {8g+x}; all 32 wave-blocks of a bh
  // are consecutive slots -> co-resident -> K/V streams are L2-hit.
  const int phys = blockIdx.x;                     // 0..2047
  const int xcd = phys & 7, slot = phys >> 3;      // slot 0..255
  const int bh  = 8 * (slot >> 5) + xcd;           // 0..63
  const int q0  = (slot & 31) * 64;                // 64-row q tile
  const int h = bh & 15, b = bh >> 4;
  const long long qstart = (long long)qsg[0];

  // ---- wave-level all-true mask check (u8 or i32 bool layouts), 32 B/lane ----
  const unsigned char* mrow = maskg + (size_t)b * SK;
  int ok_u8 = 1, ok_i32 = 1;
  {
    const unsigned int* p = (const unsigned int*)(mrow + lane * 32);
#pragma unroll
    for (int j = 0; j < 8; ++j) {
      unsigned int x = p[j];
      int a = (x & 0xFFu) && (x & 0xFF00u) && (x & 0xFF0000u) && (x & 0xFF000000u);
      ok_u8 &= a;
      ok_i32 &= (x == 1u);
    }
  }
  const bool mask_all = __all(ok_u8) || __all(ok_i32);

  const size_t tbase = (size_t)bh * NT * TILE_E;
  const unsigned short* kb = kws + tbase + lane * 8;
  const unsigned short* vb = vws + tbase + lane * 8;

  // ---- Q fragments for BOTH subtiles, CEXP pre-folded ----
  short8 qf0[8], qf1[8];
  {
    const float* qp = qg + ((size_t)b * SQ + q0 + ql) * DM + h * DH + hi8;
#pragma unroll
    for (int s = 0; s < 8; ++s) {
      float4 a0 = *(const float4*)(qp + s * 16);
      float4 c0 = *(const float4*)(qp + s * 16 + 4);
      float4 a1 = *(const float4*)(qp + 32 * DM + s * 16);
      float4 c1 = *(const float4*)(qp + 32 * DM + s * 16 + 4);
      US8 t0, t1;
      t0.u[0] = f2bf(a0.x * CEXP); t0.u[1] = f2bf(a0.y * CEXP);
      t0.u[2] = f2bf(a0.z * CEXP); t0.u[3] = f2bf(a0.w * CEXP);
      t0.u[4] = f2bf(c0.x * CEXP); t0.u[5] = f2bf(c0.y * CEXP);
      t0.u[6] = f2bf(c0.z * CEXP); t0.u[7] = f2bf(c0.w * CEXP);
      t1.u[0] = f2bf(a1.x * CEXP); t1.u[1] = f2bf(a1.y * CEXP);
      t1.u[2] = f2bf(a1.z * CEXP); t1.u[3] = f2bf(a1.w * CEXP);
      t1.u[4] = f2bf(c1.x * CEXP); t1.u[5] = f2bf(c1.y * CEXP);
      t1.u[6] = f2bf(c1.z * CEXP); t1.u[7] = f2bf(c1.w * CEXP);
      qf0[s] = t0.v; qf1[s] = t1.v;
    }
  }

  f32x16 zv;
#pragma unroll
  for (int r = 0; r < 16; ++r) zv[r] = 0.0f;
  f32x16 acc0[4], acc1[4];
#pragma unroll
  for (int n = 0; n < 4; ++n) { acc0[n] = zv; acc1[n] = zv; }
  float L0 = 0.0f, L1 = 0.0f;
  const long long qlim0 = qstart + (long long)(q0 + ql);

  short8 kfA[8], vfA[8], kfB[8], vfB[8], kfC[8], vfC[8];
  {
#pragma unroll
    for (int s = 0; s < 8; ++s) kfA[s] = *(const short8*)(kb + s * 512);
#pragma unroll
    for (int s = 0; s < 8; ++s) vfA[s] = *(const short8*)(vb + s * 512);
#pragma unroll
    for (int s = 0; s < 8; ++s) kfB[s] = *(const short8*)(kb + TILE_E + s * 512);
#pragma unroll
    for (int s = 0; s < 8; ++s) vfB[s] = *(const short8*)(vb + TILE_E + s * 512);
  }

  // one tile: prefetch(t+2)->{kfN,vfN}; compute tile t from {kfP,vfP}.
  auto step = [&](int t, short8 (&kfP)[8], short8 (&vfP)[8],
                  short8 (&kfN)[8], short8 (&vfN)[8]) {
    const int kv0 = t * KVB;
    // ---- prefetch tile t+2 (16 loads; ~2 tile-bodies of latency cover) ----
    {
      const int tn = (t + 2 < NT) ? (t + 2) : (NT - 1);
      const unsigned short* pk = kb + (size_t)tn * TILE_E;
      const unsigned short* pv = vb + (size_t)tn * TILE_E;
#pragma unroll
      for (int s = 0; s < 8; ++s) kfN[s] = *(const short8*)(pk + s * 512);
#pragma unroll
      for (int s = 0; s < 8; ++s) vfN[s] = *(const short8*)(pv + s * 512);
    }

    // ---- QK^T (swapped): each K-frag feeds BOTH q-subtiles (2 chains) ----
    f32x16 st0 = zv, st1 = zv;
    __builtin_amdgcn_s_setprio(1);
#pragma unroll
    for (int s = 0; s < 8; ++s) {
      st0 = __builtin_amdgcn_mfma_f32_32x32x16_bf16(kfP[s], qf0[s], st0, 0, 0, 0);
      st1 = __builtin_amdgcn_mfma_f32_32x32x16_bf16(kfP[s], qf1[s], st1, 0, 0, 0);
    }
    __builtin_amdgcn_s_setprio(0);

    const bool fast = mask_all && ((long long)(kv0 + KVB - 1) <= qstart + (long long)q0);

    // ---- masking (slow path only) ----
    if (!fast) {
#pragma unroll
      for (int r = 0; r < 16; ++r) {
        int nl = (r & 3) + 8 * (r >> 2) + 4 * hi;
        bool okm = (mrow[kv0 + nl] != 0);
        bool ok0 = okm && ((long long)(kv0 + nl) <= qlim0);
        bool ok1 = okm && ((long long)(kv0 + nl) <= qlim0 + 32);
        if (!ok0) st0[r] = -3.0e38f;
        if (!ok1) st1[r] = -3.0e38f;
      }
    }

    // ---- p = exp2(st)  (M == 0; pre-scaled; masked -> exp2(-3e38) = 0) ----
#pragma unroll
    for (int r = 0; r < 16; ++r) {
      st0[r] = __builtin_amdgcn_exp2f(st0[r]);
      st1[r] = __builtin_amdgcn_exp2f(st1[r]);
    }

    // ---- L += sum_k p, per subtile ----
    float s80[8], s81[8];
#pragma unroll
    for (int i = 0; i < 8; ++i) { s80[i] = st0[i] + st0[i + 8]; s81[i] = st1[i] + st1[i + 8]; }
#pragma unroll
    for (int i = 0; i < 4; ++i) { s80[i] = s80[i] + s80[i + 4]; s81[i] = s81[i] + s81[i + 4]; }
    float p0 = (s80[0] + s80[1]) + (s80[2] + s80[3]);
    float p1 = (s81[0] + s81[1]) + (s81[2] + s81[3]);
    p0 += __shfl_xor(p0, 32);
    p1 += __shfl_xor(p1, 32);
    L0 += p0; L1 += p1;

    // ---- P -> bf16 A-frags (T12): per subtile ----
    short8 pa0[2], pa1[2];
#pragma unroll
    for (int half = 0; half < 2; ++half) {
      const f32x16& sth = half ? st1 : st0;
      short8* pah = half ? pa1 : pa0;
#pragma unroll
      for (int ks = 0; ks < 2; ++ks) {
        const int m8 = ks * 8;
        unsigned int X0, X1, Y0, Y1;
        asm("v_cvt_pk_bf16_f32 %0, %1, %2" : "=v"(X0) : "v"(sth[m8 + 0]), "v"(sth[m8 + 1]));
        asm("v_cvt_pk_bf16_f32 %0, %1, %2" : "=v"(X1) : "v"(sth[m8 + 2]), "v"(sth[m8 + 3]));
        asm("v_cvt_pk_bf16_f32 %0, %1, %2" : "=v"(Y0) : "v"(sth[m8 + 4]), "v"(sth[m8 + 5]));
        asm("v_cvt_pk_bf16_f32 %0, %1, %2" : "=v"(Y1) : "v"(sth[m8 + 6]), "v"(sth[m8 + 7]));
        asm("v_permlane32_swap_b32 %0, %1" : "+v"(X0), "+v"(Y0));
        asm("v_permlane32_swap_b32 %0, %1" : "+v"(X1), "+v"(Y1));
        UP4 P;
        P.u[0] = X0; P.u[1] = X1; P.u[2] = Y0; P.u[3] = Y1;
        pah[ks] = P.v;
      }
    }

    // ---- PV: each V-frag feeds BOTH q-subtiles (8 indep chains) ----
    __builtin_amdgcn_s_setprio(1);
#pragma unroll
    for (int n = 0; n < 4; ++n) {
#pragma unroll
      for (int ks = 0; ks < 2; ++ks) {
        acc0[n] = __builtin_amdgcn_mfma_f32_32x32x16_bf16(pa0[ks], vfP[n * 2 + ks],
                                                          acc0[n], 0, 0, 0);
        acc1[n] = __builtin_amdgcn_mfma_f32_32x32x16_bf16(pa1[ks], vfP[n * 2 + ks],
                                                          acc1[n], 0, 0, 0);
      }
    }
    __builtin_amdgcn_s_setprio(0);
  };

  // 21 groups of 3 tiles (t = 0..62), rotation A,B,C returns to phase each
  // group; tile 63 is left in kfA/vfA for the tail step.
  int t = 0;
#pragma unroll 1
  for (int g = 0; g < 21; ++g, t += 3) {
    step(t,     kfA, vfA, kfC, vfC);
    step(t + 1, kfB, vfB, kfA, vfA);
    step(t + 2, kfC, vfC, kfB, vfB);
  }
  step(63, kfA, vfA, kfC, vfC);   // tail (prefetch clamped, dead)

  // ---- epilogue: out = acc / L, both subtiles ----
  if (L0 == 0.0f) L0 = 1.0f;
  if (L1 == 0.0f) L1 = 1.0f;
  float ri0 = 1.0f / L0, ri1 = 1.0f / L1;
#pragma unroll
  for (int r = 0; r < 16; ++r) {
    int cr = (r & 3) + 8 * (r >> 2) + 4 * hi;
    float i0 = __shfl(ri0, cr), i1 = __shfl(ri1, cr);
    float* op0 = outg + ((size_t)b * SQ + q0 + cr) * DM + h * DH + ql;
    float* op1 = op0 + 32 * DM;
    op0[0]  = acc0[0][r] * i0;
    op0[32] = acc0[1][r] * i0;
    op0[64] = acc0[2][r] * i0;
    op0[96] = acc0[3][r] * i0;
    op1[0]  = acc1[0][r] * i1;
    op1[32] = acc1[1][r] * i1;
    op1[64] = acc1[2][r] * i1;
    op1[96] = acc1[3][r] * i1;
  }
}

// ---------------------------------------------------------------------------
// Fallback (R1 kernel, in-kernel dequant) — used only if ws is too small.
// ---------------------------------------------------------------------------
__global__ __launch_bounds__(512, 2)
void eit3_attn_fb(const float* __restrict__ qg, const float* __restrict__ kg,
                  const float* __restrict__ vg, const unsigned char* __restrict__ maskg,
                  const int* __restrict__ qsg, float* __restrict__ outg)
{
  const int tid  = threadIdx.x;
  const int lane = tid & 63;
  const int w    = tid >> 6;
  const int hi   = lane >> 5;
  const int ql   = lane & 31;
  const int qb = blockIdx.x;
  const int h  = blockIdx.y;
  const int b  = blockIdx.z;
  const int q0 = qb * 256;
  const long long qstart = (long long)qsg[0];

  __shared__ __align__(16) unsigned short Ksh[64 * 128];
  __shared__ __align__(16) unsigned short Vsh[64 * 128];
  __shared__ unsigned char mskSh[64];

  const unsigned int vbase = (unsigned int)(size_t)(void*)Vsh;

  const unsigned char* mrow = maskg + (size_t)b * SK;
  int ok_u8, ok_i32;
  {
    const unsigned char* p4 = mrow + tid * 4;
    unsigned char b0 = p4[0], b1 = p4[1], b2 = p4[2], b3 = p4[3];
    ok_u8  = (b0 && b1 && b2 && b3);
    ok_i32 = (b0 && !b1 && !b2 && !b3);
  }
  const int a_u8  = __syncthreads_and(ok_u8);
  const int a_i32 = __syncthreads_and(ok_i32);
  const bool mask_all = (a_u8 | a_i32) != 0;

  short8 qf[8];
  {
    const int qrow = q0 + w * 32 + ql;
    const float* qp = qg + ((size_t)b * SQ + qrow) * DM + h * DH + hi * 8;
#pragma unroll
    for (int s = 0; s < 8; ++s) {
      float4 fa = *(const float4*)(qp + s * 16);
      float4 fb = *(const float4*)(qp + s * 16 + 4);
      US8 t;
      t.u[0] = f2bf(fa.x); t.u[1] = f2bf(fa.y); t.u[2] = f2bf(fa.z); t.u[3] = f2bf(fa.w);
      t.u[4] = f2bf(fb.x); t.u[5] = f2bf(fb.y); t.u[6] = f2bf(fb.z); t.u[7] = f2bf(fb.w);
      qf[s] = t.v;
    }
  }

  f32x16 zv;
#pragma unroll
  for (int r = 0; r < 16; ++r) zv[r] = 0.0f;
  f32x16 acc[4];
  acc[0] = zv; acc[1] = zv; acc[2] = zv; acc[3] = zv;
  float M = -3.0e38f, L = 0.0f;

  const float* kptr = kg + ((size_t)b * SK) * DM + h * DH;
  const float* vptr = vg + ((size_t)b * SK) * DM + h * DH;

  constexpr float CEXP2 = 0.12752051393f;
  for (int kv0 = 0; kv0 < SK; kv0 += 64) {
    __syncthreads();
#pragma unroll
    for (int j = 0; j < 2; ++j) {
      int idx = tid + 512 * j;
      int n = idx >> 4, d8 = idx & 15;
      const float* gp = kptr + (size_t)(kv0 + n) * DM + d8 * 8;
      float4 fa = *(const float4*)gp;
      float4 fb = *(const float4*)(gp + 4);
      US8 t;
      t.u[0] = dqb(fa.x); t.u[1] = dqb(fa.y); t.u[2] = dqb(fa.z); t.u[3] = dqb(fa.w);
      t.u[4] = dqb(fb.x); t.u[5] = dqb(fb.y); t.u[6] = dqb(fb.z); t.u[7] = dqb(fb.w);
      int ui = (n * 128 + d8 * 8) ^ ((n & 7) << 3);
      *(short8*)(Ksh + ui) = t.v;
    }
    {
      int kr = w * 8 + (lane & 7);
      int c3 = lane >> 3;
#pragma unroll
      for (int j = 0; j < 4; ++j) {
        int d4 = c3 + 8 * j;
        const float* gp = vptr + (size_t)(kv0 + kr) * DM + d4 * 4;
        float4 fa = *(const float4*)gp;
        ushort4 tv;
        tv.x = dqb(fa.x); tv.y = dqb(fa.y); tv.z = dqb(fa.z); tv.w = dqb(fa.w);
        int d = d4 * 4;
        int ui = ((kr >> 2) * 8 + (d >> 4)) * 64 + (kr & 3) * 16 + (d & 15);
        *(ushort4*)(Vsh + ui) = tv;
      }
    }
    const bool causal_ok = ((long long)kv0 + 63) <= (qstart + (long long)q0);
    const bool fast = mask_all && causal_ok;
    if (!fast && w == 0) mskSh[lane] = mrow[kv0 + lane];
    __syncthreads();

    f32x16 st[2];
#pragma unroll
    for (int t = 0; t < 2; ++t) {
      f32x16 sa = zv;
#pragma unroll
      for (int s = 0; s < 8; ++s) {
        int kr = t * 32 + ql;
        int ui = (kr * 128 + s * 16 + hi * 8) ^ ((kr & 7) << 3);
        short8 af = *(const short8*)(Ksh + ui);
        sa = __builtin_amdgcn_mfma_f32_32x32x16_bf16(af, qf[s], sa, 0, 0, 0);
      }
      st[t] = sa;
    }
    if (!fast) {
      const long long qlim = qstart + (long long)(q0 + w * 32 + ql);
#pragma unroll
      for (int t = 0; t < 2; ++t) {
#pragma unroll
        for (int r = 0; r < 16; ++r) {
          int nl = t * 32 + (r & 3) + 8 * (r >> 2) + 4 * hi;
          bool ok = (mskSh[nl] != 0) && ((long long)(kv0 + nl) <= qlim);
          if (!ok) st[t][r] = -3.0e38f;
        }
      }
    }
    f32x16 red;
#pragma unroll
    for (int r = 0; r < 16; ++r) red[r] = __builtin_fmaxf(st[0][r], st[1][r]);
#pragma unroll
    for (int r = 0; r < 8; ++r) red[r] = __builtin_fmaxf(red[r], red[r + 8]);
#pragma unroll
    for (int r = 0; r < 4; ++r) red[r] = __builtin_fmaxf(red[r], red[r + 4]);
    float pmax = __builtin_fmaxf(__builtin_fmaxf(red[0], red[1]),
                                 __builtin_fmaxf(red[2], red[3]));
    pmax = __builtin_fmaxf(pmax, __shfl_xor(pmax, 32));
    const float Mnew = __builtin_fmaxf(M, pmax);
    const float scale = __builtin_amdgcn_exp2f((M - Mnew) * CEXP2);
#pragma unroll
    for (int t = 0; t < 2; ++t) {
#pragma unroll
      for (int r = 0; r < 16; ++r)
        st[t][r] = __builtin_amdgcn_exp2f((st[t][r] - Mnew) * CEXP2);
    }
    if (!fast) {
      const long long qlim = qstart + (long long)(q0 + w * 32 + ql);
#pragma unroll
      for (int t = 0; t < 2; ++t) {
#pragma unroll
        for (int r = 0; r < 16; ++r) {
          int nl = t * 32 + (r & 3) + 8 * (r >> 2) + 4 * hi;
          bool ok = (mskSh[nl] != 0) && ((long long)(kv0 + nl) <= qlim);
          if (!ok) st[t][r] = 0.0f;
        }
      }
    }
    f32x16 sx;
#pragma unroll
    for (int r = 0; r < 16; ++r) sx[r] = st[0][r] + st[1][r];
#pragma unroll
    for (int r = 0; r < 8; ++r) sx[r] = sx[r] + sx[r + 8];
#pragma unroll
    for (int r = 0; r < 4; ++r) sx[r] = sx[r] + sx[r + 4];
    float ps = (sx[0] + sx[1]) + (sx[2] + sx[3]);
    ps += __shfl_xor(ps, 32);
    L = L * scale + ps;
    if (!__all(Mnew == M)) {
#pragma unroll
      for (int r = 0; r < 16; ++r) {
        float sc = __shfl(scale, (r & 3) + 8 * (r >> 2) + 4 * hi);
        acc[0][r] *= sc; acc[1][r] *= sc; acc[2][r] *= sc; acc[3][r] *= sc;
      }
    }
    M = Mnew;

    short8 pa[4];
#pragma unroll
    for (int ks = 0; ks < 4; ++ks) {
      const int t = ks >> 1;
      const int m8 = (ks & 1) * 8;
      unsigned int X0, X1, Y0, Y1;
      asm("v_cvt_pk_bf16_f32 %0, %1, %2" : "=v"(X0) : "v"(st[t][m8 + 0]), "v"(st[t][m8 + 1]));
      asm("v_cvt_pk_bf16_f32 %0, %1, %2" : "=v"(X1) : "v"(st[t][m8 + 2]), "v"(st[t][m8 + 3]));
      asm("v_cvt_pk_bf16_f32 %0, %1, %2" : "=v"(Y0) : "v"(st[t][m8 + 4]), "v"(st[t][m8 + 5]));
      asm("v_cvt_pk_bf16_f32 %0, %1, %2" : "=v"(Y1) : "v"(st[t][m8 + 6]), "v"(st[t][m8 + 7]));
      asm("v_permlane32_swap_b32 %0, %1" : "+v"(X0), "+v"(Y0));
      asm("v_permlane32_swap_b32 %0, %1" : "+v"(X1), "+v"(Y1));
      UP4 P;
      P.u[0] = X0; P.u[1] = X1; P.u[2] = Y0; P.u[3] = Y1;
      pa[ks] = P.v;
    }
#pragma unroll
    for (int n = 0; n < 4; ++n) {
      unsigned long long t0[4], t1[4];
#pragma unroll
      for (int ks = 0; ks < 4; ++ks) {
        unsigned int addr = vbase
          + (unsigned int)(((4 * ks + 2 * hi) * 8 + 2 * n + ((lane >> 4) & 1)) * 128)
          + (unsigned int)((lane & 15) * 8);
        asm volatile("ds_read_b64_tr_b16 %0, %1" : "=v"(t0[ks]) : "v"(addr));
        asm volatile("ds_read_b64_tr_b16 %0, %1 offset:1024" : "=v"(t1[ks]) : "v"(addr));
      }
      asm volatile("s_waitcnt lgkmcnt(0)" ::: "memory");
      __builtin_amdgcn_sched_barrier(0);
#pragma unroll
      for (int ks = 0; ks < 4; ++ks) {
        union { unsigned long long q[2]; short8 v; } vb2;
        vb2.q[0] = t0[ks]; vb2.q[1] = t1[ks];
        acc[n] = __builtin_amdgcn_mfma_f32_32x32x16_bf16(pa[ks], vb2.v, acc[n], 0, 0, 0);
      }
    }
  }

  if (L == 0.0f) L = 1.0f;
  float rinv = 1.0f / L;
#pragma unroll
  for (int r = 0; r < 16; ++r) {
    int cr = (r & 3) + 8 * (r >> 2) + 4 * hi;
    float inv = __shfl(rinv, cr);
    float* op = outg + ((size_t)b * SQ + (q0 + w * 32 + cr)) * DM + h * DH + ql;
    op[0]  = acc[0][r] * inv;
    op[32] = acc[1][r] * inv;
    op[64] = acc[2][r] * inv;
    op[96] = acc[3][r] * inv;
  }
}

extern "C" void kernel_launch(void* const* d_in, const int* in_sizes, int n_in,
                              void* d_out, int out_size, void* d_ws, size_t ws_size,
                              hipStream_t stream) {
  (void)in_sizes; (void)n_in; (void)out_size;
  const float* q = (const float*)d_in[0];
  const float* k = (const float*)d_in[1];
  const float* v = (const float*)d_in[2];
  const unsigned char* mask = (const unsigned char*)d_in[3];
  const int* qs = (const int*)d_in[4];

  const size_t need = (size_t)2 * 16777216 * 2;   // K + V bf16 = 64 MiB
  if (ws_size >= need) {
    unsigned short* kws = (unsigned short*)d_ws;
    unsigned short* vws = kws + 16777216;
    dim3 pgrid(NT, 16, 4);
    eit3_pre<<<pgrid, dim3(512), 0, stream>>>(k, v, kws, vws);
    eit3_attn<<<dim3(2048), dim3(64), 0, stream>>>(kws, vws, q, mask, qs, (float*)d_out);
  } else {
    dim3 grid(SQ / 256, 16, 4);
    eit3_attn_fb<<<grid, dim3(512), 0, stream>>>(q, k, v, mask, qs, (float*)d_out);
  }
}

// Round 13
// 194.729 us; speedup vs baseline: 1.0525x; 1.0525x over previous
//
#include <hip/hip_runtime.h>

// EIT3Attention: B=4, Sq=Sk=2048, d_model=2048, H=16, Dh=128, fp32 I/O.
// R13 = R11 exact revert (best known: 201us total / 176us main).
// 64 q-rows per wave (2 subtiles), KVB=32, no-LDS fragment-direct ws reads,
// M==0 softmax (CEXP folded into Q), K/V register-double-buffered (dist 1).
// R12 lesson: prefetch distance 2 exceeded the 256-VGPR arch file (hit cap,
// 194us); distance 1 already covers L2 latency. Remaining gap to the 62us
// MFMA floor is operand-return serialization at 1 wave/SIMD — needs
// disasm-level scheduling, out of scope.

typedef __attribute__((ext_vector_type(8))) short short8;
typedef __attribute__((ext_vector_type(16))) float f32x16;

#define DEVI __device__ __forceinline__

namespace {

constexpr int DM = 2048;   // d_model
constexpr int SQ = 2048;
constexpr int SK = 2048;
constexpr int DH = 128;
constexpr int KVB = 32;            // kv rows per tile
constexpr int NT = SK / KVB;       // 64 tiles
constexpr int TILE_E = KVB * DH;   // 4096 elems per tensor-tile
// (1/sqrt(128)) * log2(e), folded into Q at conversion
constexpr float CEXP = 0.12752051393f;

union US8 { unsigned short u[8]; short8 v; };
union UP4 { unsigned int u[4]; short8 v; };

DEVI unsigned short f2bf(float f) {            // fp32 -> bf16 RNE
  unsigned int u = __float_as_uint(f);
  return (unsigned short)((u + 0x7fffu + ((u >> 16) & 1u)) >> 16);
}

DEVI float dq(float x) {                       // int4 quant-dequant, matches ref
  float t = __builtin_rintf(__builtin_fmaf(x, 20.0f, 8.0f));  // round half-even
  t = __builtin_fmaxf(t, 0.0f);
  t = __builtin_fminf(t, 15.0f);
  return (t - 8.0f) * 0.05f;
}

DEVI unsigned short dqb(float x) { return f2bf(dq(x)); }

} // namespace

// ---------------------------------------------------------------------------
// Prepass (verified R8-R12): dequant K/V -> bf16 ws in MFMA-fragment order.
// Per (bh, tile t of 32 rows), granule g2 = tid (0..511), 8 elems each:
//  K: frag s = g2>>6, lane l = g2&63: Kd[t*32 + (l&31)][s*16 + (l>>5)*8 + j]
//  V: f = g2>>6 (n=f>>1, ks=f&1): Vd[t*32 + ks*16 + (l>>5)*8 + j][n*32 + (l&31)]
// ---------------------------------------------------------------------------
__global__ __launch_bounds__(512)
void eit3_pre(const float* __restrict__ kg, const float* __restrict__ vg,
              unsigned short* __restrict__ kws, unsigned short* __restrict__ vws)
{
  const int tid = threadIdx.x;
  const int t = blockIdx.x, h = blockIdx.y, b = blockIdx.z;
  const size_t tb = (((size_t)(b * 16 + h)) * NT + t) * TILE_E;
  __shared__ __align__(16) unsigned short KL[32 * 136];  // rows 16B-aligned
  __shared__ __align__(16) unsigned short VL[32 * 136];

  {
    const int r = tid >> 4, c8 = (tid & 15) * 8;
    const float* ks = kg + ((size_t)b * SK + (size_t)t * KVB + r) * DM + h * DH + c8;
    const float* vs = vg + ((size_t)b * SK + (size_t)t * KVB + r) * DM + h * DH + c8;
    float4 ka = *(const float4*)ks, kb4 = *(const float4*)(ks + 4);
    float4 va = *(const float4*)vs, vb4 = *(const float4*)(vs + 4);
    US8 ok, ov;
    ok.u[0] = dqb(ka.x); ok.u[1] = dqb(ka.y); ok.u[2] = dqb(ka.z); ok.u[3] = dqb(ka.w);
    ok.u[4] = dqb(kb4.x); ok.u[5] = dqb(kb4.y); ok.u[6] = dqb(kb4.z); ok.u[7] = dqb(kb4.w);
    ov.u[0] = dqb(va.x); ov.u[1] = dqb(va.y); ov.u[2] = dqb(va.z); ov.u[3] = dqb(va.w);
    ov.u[4] = dqb(vb4.x); ov.u[5] = dqb(vb4.y); ov.u[6] = dqb(vb4.z); ov.u[7] = dqb(vb4.w);
    *(short8*)(KL + r * 136 + c8) = ok.v;
    *(short8*)(VL + r * 136 + c8) = ov.v;
  }
  __syncthreads();

  const int l = tid & 63;
  const int lq = l & 31, lh = (l >> 5) * 8;
  {
    const int s = tid >> 6;
    short8 o = *(const short8*)(KL + lq * 136 + s * 16 + lh);
    *(short8*)(kws + tb + (size_t)tid * 8) = o;
  }
  {
    const int f = tid >> 6, n = f >> 1, ks2 = f & 1;
    US8 o;
#pragma unroll
    for (int j = 0; j < 8; ++j)
      o.u[j] = VL[(ks2 * 16 + lh + j) * 136 + n * 32 + lq];
    *(short8*)(vws + tb + (size_t)tid * 8) = o.v;
  }
}

// ---------------------------------------------------------------------------
// Main attention kernel: 1 wave/block, 64 q-rows (2 subtiles), KVB=32,
// zero LDS, M==0 softmax, register-double-buffered K/V fragments.
// ---------------------------------------------------------------------------
__global__ __launch_bounds__(64)
void eit3_attn(const unsigned short* __restrict__ kws,
               const unsigned short* __restrict__ vws,
               const float* __restrict__ qg,
               const unsigned char* __restrict__ maskg,
               const int* __restrict__ qsg, float* __restrict__ outg)
{
  const int lane = threadIdx.x;
  const int hi   = lane >> 5;
  const int ql   = lane & 31;
  const int hi8  = hi * 8;
  // XCD-grouped decode: XCD x owns bh in {8g+x}; all 32 wave-blocks of a bh
  // are consecutive slots -> co-resident -> K/V streams are L2-hit.
  const int phys = blockIdx.x;                     // 0..2047
  const int xcd = phys & 7, slot = phys >> 3;      // slot 0..255
  const int bh  = 8 * (slot >> 5) + xcd;           // 0..63
  const int q0  = (slot & 31) * 64;                // 64-row q tile
  const int h = bh & 15, b = bh >> 4;
  const long long qstart = (long long)qsg[0];

  // ---- wave-level all-true mask check (u8 or i32 bool layouts), 32 B/lane ----
  const unsigned char* mrow = maskg + (size_t)b * SK;
  int ok_u8 = 1, ok_i32 = 1;
  {
    const unsigned int* p = (const unsigned int*)(mrow + lane * 32);
#pragma unroll
    for (int j = 0; j < 8; ++j) {
      unsigned int x = p[j];
      int a = (x & 0xFFu) && (x & 0xFF00u) && (x & 0xFF0000u) && (x & 0xFF000000u);
      ok_u8 &= a;
      ok_i32 &= (x == 1u);
    }
  }
  const bool mask_all = __all(ok_u8) || __all(ok_i32);

  const size_t tbase = (size_t)bh * NT * TILE_E;
  const unsigned short* kb = kws + tbase + lane * 8;
  const unsigned short* vb = vws + tbase + lane * 8;

  // ---- Q fragments for BOTH subtiles, CEXP pre-folded ----
  short8 qf0[8], qf1[8];
  {
    const float* qp = qg + ((size_t)b * SQ + q0 + ql) * DM + h * DH + hi8;
#pragma unroll
    for (int s = 0; s < 8; ++s) {
      float4 a0 = *(const float4*)(qp + s * 16);
      float4 c0 = *(const float4*)(qp + s * 16 + 4);
      float4 a1 = *(const float4*)(qp + 32 * DM + s * 16);
      float4 c1 = *(const float4*)(qp + 32 * DM + s * 16 + 4);
      US8 t0, t1;
      t0.u[0] = f2bf(a0.x * CEXP); t0.u[1] = f2bf(a0.y * CEXP);
      t0.u[2] = f2bf(a0.z * CEXP); t0.u[3] = f2bf(a0.w * CEXP);
      t0.u[4] = f2bf(c0.x * CEXP); t0.u[5] = f2bf(c0.y * CEXP);
      t0.u[6] = f2bf(c0.z * CEXP); t0.u[7] = f2bf(c0.w * CEXP);
      t1.u[0] = f2bf(a1.x * CEXP); t1.u[1] = f2bf(a1.y * CEXP);
      t1.u[2] = f2bf(a1.z * CEXP); t1.u[3] = f2bf(a1.w * CEXP);
      t1.u[4] = f2bf(c1.x * CEXP); t1.u[5] = f2bf(c1.y * CEXP);
      t1.u[6] = f2bf(c1.z * CEXP); t1.u[7] = f2bf(c1.w * CEXP);
      qf0[s] = t0.v; qf1[s] = t1.v;
    }
  }

  f32x16 zv;
#pragma unroll
  for (int r = 0; r < 16; ++r) zv[r] = 0.0f;
  f32x16 acc0[4], acc1[4];
#pragma unroll
  for (int n = 0; n < 4; ++n) { acc0[n] = zv; acc1[n] = zv; }
  float L0 = 0.0f, L1 = 0.0f;
  const long long qlim0 = qstart + (long long)(q0 + ql);

  short8 kfA[8], vfA[8], kfB[8], vfB[8];
  {
#pragma unroll
    for (int s = 0; s < 8; ++s) kfA[s] = *(const short8*)(kb + s * 512);
#pragma unroll
    for (int s = 0; s < 8; ++s) vfA[s] = *(const short8*)(vb + s * 512);
  }

  // one tile: prefetch(t+1)->{kfN,vfN}; compute tile t from {kfP,vfP}.
  auto step = [&](int t, short8 (&kfP)[8], short8 (&vfP)[8],
                  short8 (&kfN)[8], short8 (&vfN)[8]) {
    const int kv0 = t * KVB;
    // ---- prefetch tile t+1 (16 loads; latency hides under compute) ----
    {
      const int tn = (t + 1 < NT) ? (t + 1) : (NT - 1);
      const unsigned short* pk = kb + (size_t)tn * TILE_E;
      const unsigned short* pv = vb + (size_t)tn * TILE_E;
#pragma unroll
      for (int s = 0; s < 8; ++s) kfN[s] = *(const short8*)(pk + s * 512);
#pragma unroll
      for (int s = 0; s < 8; ++s) vfN[s] = *(const short8*)(pv + s * 512);
    }

    // ---- QK^T (swapped): each K-frag feeds BOTH q-subtiles (2 chains) ----
    f32x16 st0 = zv, st1 = zv;
    __builtin_amdgcn_s_setprio(1);
#pragma unroll
    for (int s = 0; s < 8; ++s) {
      st0 = __builtin_amdgcn_mfma_f32_32x32x16_bf16(kfP[s], qf0[s], st0, 0, 0, 0);
      st1 = __builtin_amdgcn_mfma_f32_32x32x16_bf16(kfP[s], qf1[s], st1, 0, 0, 0);
    }
    __builtin_amdgcn_s_setprio(0);

    const bool fast = mask_all && ((long long)(kv0 + KVB - 1) <= qstart + (long long)q0);

    // ---- masking (slow path only) ----
    if (!fast) {
#pragma unroll
      for (int r = 0; r < 16; ++r) {
        int nl = (r & 3) + 8 * (r >> 2) + 4 * hi;
        bool okm = (mrow[kv0 + nl] != 0);
        bool ok0 = okm && ((long long)(kv0 + nl) <= qlim0);
        bool ok1 = okm && ((long long)(kv0 + nl) <= qlim0 + 32);
        if (!ok0) st0[r] = -3.0e38f;
        if (!ok1) st1[r] = -3.0e38f;
      }
    }

    // ---- p = exp2(st)  (M == 0; pre-scaled; masked -> exp2(-3e38) = 0) ----
#pragma unroll
    for (int r = 0; r < 16; ++r) {
      st0[r] = __builtin_amdgcn_exp2f(st0[r]);
      st1[r] = __builtin_amdgcn_exp2f(st1[r]);
    }

    // ---- L += sum_k p, per subtile ----
    float s80[8], s81[8];
#pragma unroll
    for (int i = 0; i < 8; ++i) { s80[i] = st0[i] + st0[i + 8]; s81[i] = st1[i] + st1[i + 8]; }
#pragma unroll
    for (int i = 0; i < 4; ++i) { s80[i] = s80[i] + s80[i + 4]; s81[i] = s81[i] + s81[i + 4]; }
    float p0 = (s80[0] + s80[1]) + (s80[2] + s80[3]);
    float p1 = (s81[0] + s81[1]) + (s81[2] + s81[3]);
    p0 += __shfl_xor(p0, 32);
    p1 += __shfl_xor(p1, 32);
    L0 += p0; L1 += p1;

    // ---- P -> bf16 A-frags (T12): per subtile ----
    short8 pa0[2], pa1[2];
#pragma unroll
    for (int half = 0; half < 2; ++half) {
      const f32x16& sth = half ? st1 : st0;
      short8* pah = half ? pa1 : pa0;
#pragma unroll
      for (int ks = 0; ks < 2; ++ks) {
        const int m8 = ks * 8;
        unsigned int X0, X1, Y0, Y1;
        asm("v_cvt_pk_bf16_f32 %0, %1, %2" : "=v"(X0) : "v"(sth[m8 + 0]), "v"(sth[m8 + 1]));
        asm("v_cvt_pk_bf16_f32 %0, %1, %2" : "=v"(X1) : "v"(sth[m8 + 2]), "v"(sth[m8 + 3]));
        asm("v_cvt_pk_bf16_f32 %0, %1, %2" : "=v"(Y0) : "v"(sth[m8 + 4]), "v"(sth[m8 + 5]));
        asm("v_cvt_pk_bf16_f32 %0, %1, %2" : "=v"(Y1) : "v"(sth[m8 + 6]), "v"(sth[m8 + 7]));
        asm("v_permlane32_swap_b32 %0, %1" : "+v"(X0), "+v"(Y0));
        asm("v_permlane32_swap_b32 %0, %1" : "+v"(X1), "+v"(Y1));
        UP4 P;
        P.u[0] = X0; P.u[1] = X1; P.u[2] = Y0; P.u[3] = Y1;
        pah[ks] = P.v;
      }
    }

    // ---- PV: each V-frag feeds BOTH q-subtiles (8 indep chains) ----
    __builtin_amdgcn_s_setprio(1);
#pragma unroll
    for (int n = 0; n < 4; ++n) {
#pragma unroll
      for (int ks = 0; ks < 2; ++ks) {
        acc0[n] = __builtin_amdgcn_mfma_f32_32x32x16_bf16(pa0[ks], vfP[n * 2 + ks],
                                                          acc0[n], 0, 0, 0);
        acc1[n] = __builtin_amdgcn_mfma_f32_32x32x16_bf16(pa1[ks], vfP[n * 2 + ks],
                                                          acc1[n], 0, 0, 0);
      }
    }
    __builtin_amdgcn_s_setprio(0);
  };

  for (int t = 0; t < NT; t += 2) {   // NT even
    step(t,     kfA, vfA, kfB, vfB);
    step(t + 1, kfB, vfB, kfA, vfA);
  }

  // ---- epilogue: out = acc / L, both subtiles ----
  if (L0 == 0.0f) L0 = 1.0f;
  if (L1 == 0.0f) L1 = 1.0f;
  float ri0 = 1.0f / L0, ri1 = 1.0f / L1;
#pragma unroll
  for (int r = 0; r < 16; ++r) {
    int cr = (r & 3) + 8 * (r >> 2) + 4 * hi;
    float i0 = __shfl(ri0, cr), i1 = __shfl(ri1, cr);
    float* op0 = outg + ((size_t)b * SQ + q0 + cr) * DM + h * DH + ql;
    float* op1 = op0 + 32 * DM;
    op0[0]  = acc0[0][r] * i0;
    op0[32] = acc0[1][r] * i0;
    op0[64] = acc0[2][r] * i0;
    op0[96] = acc0[3][r] * i0;
    op1[0]  = acc1[0][r] * i1;
    op1[32] = acc1[1][r] * i1;
    op1[64] = acc1[2][r] * i1;
    op1[96] = acc1[3][r] * i1;
  }
}

// ---------------------------------------------------------------------------
// Fallback (R1 kernel, in-kernel dequant) — used only if ws is too small.
// ---------------------------------------------------------------------------
__global__ __launch_bounds__(512, 2)
void eit3_attn_fb(const float* __restrict__ qg, const float* __restrict__ kg,
                  const float* __restrict__ vg, const unsigned char* __restrict__ maskg,
                  const int* __restrict__ qsg, float* __restrict__ outg)
{
  const int tid  = threadIdx.x;
  const int lane = tid & 63;
  const int w    = tid >> 6;
  const int hi   = lane >> 5;
  const int ql   = lane & 31;
  const int qb = blockIdx.x;
  const int h  = blockIdx.y;
  const int b  = blockIdx.z;
  const int q0 = qb * 256;
  const long long qstart = (long long)qsg[0];

  __shared__ __align__(16) unsigned short Ksh[64 * 128];
  __shared__ __align__(16) unsigned short Vsh[64 * 128];
  __shared__ unsigned char mskSh[64];

  const unsigned int vbase = (unsigned int)(size_t)(void*)Vsh;

  const unsigned char* mrow = maskg + (size_t)b * SK;
  int ok_u8, ok_i32;
  {
    const unsigned char* p4 = mrow + tid * 4;
    unsigned char b0 = p4[0], b1 = p4[1], b2 = p4[2], b3 = p4[3];
    ok_u8  = (b0 && b1 && b2 && b3);
    ok_i32 = (b0 && !b1 && !b2 && !b3);
  }
  const int a_u8  = __syncthreads_and(ok_u8);
  const int a_i32 = __syncthreads_and(ok_i32);
  const bool mask_all = (a_u8 | a_i32) != 0;

  short8 qf[8];
  {
    const int qrow = q0 + w * 32 + ql;
    const float* qp = qg + ((size_t)b * SQ + qrow) * DM + h * DH + hi * 8;
#pragma unroll
    for (int s = 0; s < 8; ++s) {
      float4 fa = *(const float4*)(qp + s * 16);
      float4 fb = *(const float4*)(qp + s * 16 + 4);
      US8 t;
      t.u[0] = f2bf(fa.x); t.u[1] = f2bf(fa.y); t.u[2] = f2bf(fa.z); t.u[3] = f2bf(fa.w);
      t.u[4] = f2bf(fb.x); t.u[5] = f2bf(fb.y); t.u[6] = f2bf(fb.z); t.u[7] = f2bf(fb.w);
      qf[s] = t.v;
    }
  }

  f32x16 zv;
#pragma unroll
  for (int r = 0; r < 16; ++r) zv[r] = 0.0f;
  f32x16 acc[4];
  acc[0] = zv; acc[1] = zv; acc[2] = zv; acc[3] = zv;
  float M = -3.0e38f, L = 0.0f;

  const float* kptr = kg + ((size_t)b * SK) * DM + h * DH;
  const float* vptr = vg + ((size_t)b * SK) * DM + h * DH;

  constexpr float CEXP2 = 0.12752051393f;
  for (int kv0 = 0; kv0 < SK; kv0 += 64) {
    __syncthreads();
#pragma unroll
    for (int j = 0; j < 2; ++j) {
      int idx = tid + 512 * j;
      int n = idx >> 4, d8 = idx & 15;
      const float* gp = kptr + (size_t)(kv0 + n) * DM + d8 * 8;
      float4 fa = *(const float4*)gp;
      float4 fb = *(const float4*)(gp + 4);
      US8 t;
      t.u[0] = dqb(fa.x); t.u[1] = dqb(fa.y); t.u[2] = dqb(fa.z); t.u[3] = dqb(fa.w);
      t.u[4] = dqb(fb.x); t.u[5] = dqb(fb.y); t.u[6] = dqb(fb.z); t.u[7] = dqb(fb.w);
      int ui = (n * 128 + d8 * 8) ^ ((n & 7) << 3);
      *(short8*)(Ksh + ui) = t.v;
    }
    {
      int kr = w * 8 + (lane & 7);
      int c3 = lane >> 3;
#pragma unroll
      for (int j = 0; j < 4; ++j) {
        int d4 = c3 + 8 * j;
        const float* gp = vptr + (size_t)(kv0 + kr) * DM + d4 * 4;
        float4 fa = *(const float4*)gp;
        ushort4 tv;
        tv.x = dqb(fa.x); tv.y = dqb(fa.y); tv.z = dqb(fa.z); tv.w = dqb(fa.w);
        int d = d4 * 4;
        int ui = ((kr >> 2) * 8 + (d >> 4)) * 64 + (kr & 3) * 16 + (d & 15);
        *(ushort4*)(Vsh + ui) = tv;
      }
    }
    const bool causal_ok = ((long long)kv0 + 63) <= (qstart + (long long)q0);
    const bool fast = mask_all && causal_ok;
    if (!fast && w == 0) mskSh[lane] = mrow[kv0 + lane];
    __syncthreads();

    f32x16 st[2];
#pragma unroll
    for (int t = 0; t < 2; ++t) {
      f32x16 sa = zv;
#pragma unroll
      for (int s = 0; s < 8; ++s) {
        int kr = t * 32 + ql;
        int ui = (kr * 128 + s * 16 + hi * 8) ^ ((kr & 7) << 3);
        short8 af = *(const short8*)(Ksh + ui);
        sa = __builtin_amdgcn_mfma_f32_32x32x16_bf16(af, qf[s], sa, 0, 0, 0);
      }
      st[t] = sa;
    }
    if (!fast) {
      const long long qlim = qstart + (long long)(q0 + w * 32 + ql);
#pragma unroll
      for (int t = 0; t < 2; ++t) {
#pragma unroll
        for (int r = 0; r < 16; ++r) {
          int nl = t * 32 + (r & 3) + 8 * (r >> 2) + 4 * hi;
          bool ok = (mskSh[nl] != 0) && ((long long)(kv0 + nl) <= qlim);
          if (!ok) st[t][r] = -3.0e38f;
        }
      }
    }
    f32x16 red;
#pragma unroll
    for (int r = 0; r < 16; ++r) red[r] = __builtin_fmaxf(st[0][r], st[1][r]);
#pragma unroll
    for (int r = 0; r < 8; ++r) red[r] = __builtin_fmaxf(red[r], red[r + 8]);
#pragma unroll
    for (int r = 0; r < 4; ++r) red[r] = __builtin_fmaxf(red[r], red[r + 4]);
    float pmax = __builtin_fmaxf(__builtin_fmaxf(red[0], red[1]),
                                 __builtin_fmaxf(red[2], red[3]));
    pmax = __builtin_fmaxf(pmax, __shfl_xor(pmax, 32));
    const float Mnew = __builtin_fmaxf(M, pmax);
    const float scale = __builtin_amdgcn_exp2f((M - Mnew) * CEXP2);
#pragma unroll
    for (int t = 0; t < 2; ++t) {
#pragma unroll
      for (int r = 0; r < 16; ++r)
        st[t][r] = __builtin_amdgcn_exp2f((st[t][r] - Mnew) * CEXP2);
    }
    if (!fast) {
      const long long qlim = qstart + (long long)(q0 + w * 32 + ql);
#pragma unroll
      for (int t = 0; t < 2; ++t) {
#pragma unroll
        for (int r = 0; r < 16; ++r) {
          int nl = t * 32 + (r & 3) + 8 * (r >> 2) + 4 * hi;
          bool ok = (mskSh[nl] != 0) && ((long long)(kv0 + nl) <= qlim);
          if (!ok) st[t][r] = 0.0f;
        }
      }
    }
    f32x16 sx;
#pragma unroll
    for (int r = 0; r < 16; ++r) sx[r] = st[0][r] + st[1][r];
#pragma unroll
    for (int r = 0; r < 8; ++r) sx[r] = sx[r] + sx[r + 8];
#pragma unroll
    for (int r = 0; r < 4; ++r) sx[r] = sx[r] + sx[r + 4];
    float ps = (sx[0] + sx[1]) + (sx[2] + sx[3]);
    ps += __shfl_xor(ps, 32);
    L = L * scale + ps;
    if (!__all(Mnew == M)) {
#pragma unroll
      for (int r = 0; r < 16; ++r) {
        float sc = __shfl(scale, (r & 3) + 8 * (r >> 2) + 4 * hi);
        acc[0][r] *= sc; acc[1][r] *= sc; acc[2][r] *= sc; acc[3][r] *= sc;
      }
    }
    M = Mnew;

    short8 pa[4];
#pragma unroll
    for (int ks = 0; ks < 4; ++ks) {
      const int t = ks >> 1;
      const int m8 = (ks & 1) * 8;
      unsigned int X0, X1, Y0, Y1;
      asm("v_cvt_pk_bf16_f32 %0, %1, %2" : "=v"(X0) : "v"(st[t][m8 + 0]), "v"(st[t][m8 + 1]));
      asm("v_cvt_pk_bf16_f32 %0, %1, %2" : "=v"(X1) : "v"(st[t][m8 + 2]), "v"(st[t][m8 + 3]));
      asm("v_cvt_pk_bf16_f32 %0, %1, %2" : "=v"(Y0) : "v"(st[t][m8 + 4]), "v"(st[t][m8 + 5]));
      asm("v_cvt_pk_bf16_f32 %0, %1, %2" : "=v"(Y1) : "v"(st[t][m8 + 6]), "v"(st[t][m8 + 7]));
      asm("v_permlane32_swap_b32 %0, %1" : "+v"(X0), "+v"(Y0));
      asm("v_permlane32_swap_b32 %0, %1" : "+v"(X1), "+v"(Y1));
      UP4 P;
      P.u[0] = X0; P.u[1] = X1; P.u[2] = Y0; P.u[3] = Y1;
      pa[ks] = P.v;
    }
#pragma unroll
    for (int n = 0; n < 4; ++n) {
      unsigned long long t0[4], t1[4];
#pragma unroll
      for (int ks = 0; ks < 4; ++ks) {
        unsigned int addr = vbase
          + (unsigned int)(((4 * ks + 2 * hi) * 8 + 2 * n + ((lane >> 4) & 1)) * 128)
          + (unsigned int)((lane & 15) * 8);
        asm volatile("ds_read_b64_tr_b16 %0, %1" : "=v"(t0[ks]) : "v"(addr));
        asm volatile("ds_read_b64_tr_b16 %0, %1 offset:1024" : "=v"(t1[ks]) : "v"(addr));
      }
      asm volatile("s_waitcnt lgkmcnt(0)" ::: "memory");
      __builtin_amdgcn_sched_barrier(0);
#pragma unroll
      for (int ks = 0; ks < 4; ++ks) {
        union { unsigned long long q[2]; short8 v; } vb2;
        vb2.q[0] = t0[ks]; vb2.q[1] = t1[ks];
        acc[n] = __builtin_amdgcn_mfma_f32_32x32x16_bf16(pa[ks], vb2.v, acc[n], 0, 0, 0);
      }
    }
  }

  if (L == 0.0f) L = 1.0f;
  float rinv = 1.0f / L;
#pragma unroll
  for (int r = 0; r < 16; ++r) {
    int cr = (r & 3) + 8 * (r >> 2) + 4 * hi;
    float inv = __shfl(rinv, cr);
    float* op = outg + ((size_t)b * SQ + (q0 + w * 32 + cr)) * DM + h * DH + ql;
    op[0]  = acc[0][r] * inv;
    op[32] = acc[1][r] * inv;
    op[64] = acc[2][r] * inv;
    op[96] = acc[3][r] * inv;
  }
}

extern "C" void kernel_launch(void* const* d_in, const int* in_sizes, int n_in,
                              void* d_out, int out_size, void* d_ws, size_t ws_size,
                              hipStream_t stream) {
  (void)in_sizes; (void)n_in; (void)out_size;
  const float* q = (const float*)d_in[0];
  const float* k = (const float*)d_in[1];
  const float* v = (const float*)d_in[2];
  const unsigned char* mask = (const unsigned char*)d_in[3];
  const int* qs = (const int*)d_in[4];

  const size_t need = (size_t)2 * 16777216 * 2;   // K + V bf16 = 64 MiB
  if (ws_size >= need) {
    unsigned short* kws = (unsigned short*)d_ws;
    unsigned short* vws = kws + 16777216;
    dim3 pgrid(NT, 16, 4);
    eit3_pre<<<pgrid, dim3(512), 0, stream>>>(k, v, kws, vws);
    eit3_attn<<<dim3(2048), dim3(64), 0, stream>>>(kws, vws, q, mask, qs, (float*)d_out);
  } else {
    dim3 grid(SQ / 256, 16, 4);
    eit3_attn_fb<<<grid, dim3(512), 0, stream>>>(q, k, v, mask, qs, (float*)d_out);
  }
}